// Round 5
// baseline (361.242 us; speedup 1.0000x reference)
//
#include <hip/hip_runtime.h>
#include <hip/hip_bf16.h>

typedef __bf16 bf16_t;
typedef __attribute__((ext_vector_type(8))) __bf16 bf16x8;
typedef __attribute__((ext_vector_type(4))) float f32x4;

#define C_IN   256
#define C_OUT  512
#define HW     3136      // 56*56
#define NB     32        // batch
#define HP     58        // 56 + 2 halo
#define NQBLK  36864     // (512*256*9)/32 quant blocks

// conv-GEMM geometry: BM=256 (co), BN=224 (4 image rows x 56), BK=32, 72 K-tiles (8 ci-chunks x 9 pos)
#define BK   32
#define NWG  896         // 448 s-bands (32 img x 14) x 2 co-blocks

// ---- async global->LDS, 16B per lane (dest = wave-uniform base + lane*16; source per-lane) ----
typedef const __attribute__((address_space(1))) unsigned int gu32;
typedef __attribute__((address_space(3))) unsigned int lu32;
__device__ __forceinline__ void gl16(const void* g, void* l) {
    __builtin_amdgcn_global_load_lds((gu32*)g, (lu32*)l, 16, 0, 0);
}
#define BAR()    __builtin_amdgcn_s_barrier()
#define PRIO(x)  __builtin_amdgcn_s_setprio(x)
#define SCHED0() __builtin_amdgcn_sched_barrier(0)

// ---------------- kernel 1: 6-bit fake-quant + repack to Wt[p][co][ci] (bf16) ----------------
__global__ void k_dequant(const float* __restrict__ w, bf16_t* __restrict__ wt) {
    int b = blockIdx.x * blockDim.x + threadIdx.x;
    if (b >= NQBLK) return;
    const float* src = w + (size_t)b * 32;
    float v[32];
    float amax = 0.f;
    #pragma unroll
    for (int i = 0; i < 32; i += 4) {
        float4 t = *reinterpret_cast<const float4*>(src + i);
        v[i] = t.x; v[i+1] = t.y; v[i+2] = t.z; v[i+3] = t.w;
        amax = fmaxf(amax, fmaxf(fmaxf(fabsf(t.x), fabsf(t.y)),
                                 fmaxf(fabsf(t.z), fabsf(t.w))));
    }
    float scale = amax / 31.0f;
    if (scale == 0.f) scale = 1.f;
    #pragma unroll
    for (int i = 0; i < 32; i++) {
        float q = rintf(v[i] / scale);            // jnp.round = RNE = rintf
        q = fminf(31.f, fmaxf(-32.f, q));
        float dq = q * scale;
        int flat = b * 32 + i;                    // flat over OIHW
        int p    = flat % 9;
        int rest = flat / 9;
        int ci   = rest & 255;
        int co   = rest >> 8;
        wt[((size_t)(p * C_OUT + co) << 8) + ci] = (bf16_t)dq;
    }
}

// ---------------- kernel 1b: zero the 1-pixel halo ring of xT ----------------
__global__ void k_halo_zero(bf16_t* __restrict__ xT) {
    int idx = blockIdx.x * 256 + threadIdx.x;
    if (idx >= NB * 228 * 32) return;
    int c8 = idx & 31;
    int t  = idx >> 5;
    int p  = t % 228;
    int n  = t / 228;
    int hh, ww;
    if      (p < 58)  { hh = 0;           ww = p; }
    else if (p < 116) { hh = 57;          ww = p - 58; }
    else if (p < 172) { hh = p - 116 + 1; ww = 0; }
    else              { hh = p - 172 + 1; ww = 57; }
    size_t e = (((size_t)n * HP + hh) * HP + ww) * C_IN + c8 * 8;
    *reinterpret_cast<uint4*>(xT + e) = make_uint4(0, 0, 0, 0);
}

// ------- kernel 2: x NCHW fp32 -> halo-padded NHWC bf16 (xT[n][58][58][ci]) -------
__global__ void k_x_nhwc(const float* __restrict__ x, bf16_t* __restrict__ xT) {
    __shared__ float tile[64][65];
    const int n   = blockIdx.z;
    const int cb  = blockIdx.y * 64;
    const int hwb = blockIdx.x * 64;
    const int t   = threadIdx.x;

    const int col = t & 63;
    const int r0  = t >> 6;
    #pragma unroll
    for (int k = 0; k < 16; k++) {
        int r = r0 * 16 + k;
        tile[r][col] = x[((size_t)(n * C_IN + cb + r)) * HW + hwb + col];
    }
    __syncthreads();

    const int j  = t >> 2;
    const int co = (t & 3) * 16;
    const int hw = hwb + j;
    const int hh = hw / 56, ww = hw - hh * 56;
    __align__(16) bf16_t vals[16];
    #pragma unroll
    for (int k = 0; k < 16; k++)
        vals[k] = (bf16_t)tile[co + k][j];
    bf16_t* dst = xT + (((size_t)n * HP + hh + 1) * HP + (ww + 1)) * C_IN + cb + co;
    *reinterpret_cast<uint4*>(dst)     = *reinterpret_cast<uint4*>(&vals[0]);
    *reinterpret_cast<uint4*>(dst + 8) = *reinterpret_cast<uint4*>(&vals[8]);
}

// ---------------- kernel 3: implicit-GEMM conv, triple-buffered deep pipeline ----------------
// 8 waves as 4(M) x 2(N): wave tile = 64(co) x 112(px); acc[4][7] f32x4; K-tile = 32 ci, one pos.
// A (weights): TRIPLE buffer [3][256][32]; tile t reads slot t%3; during tile t we stage
//              A(t+2) into slot (t+2)%3 -- untouched by readers of t and t+1: race-free.
// B (pixels):  halo band [2][384][32], one ci-chunk (32) x 6 padded rows x 58 px; band c+1
//              staged in 3 parts at p=1,2,3 of chunk c; read from p=0 of chunk c+1 (5+ tiles later).
// Drain: uniform s_waitcnt vmcnt(2) per tile ("2 newest survive" = this tile's A-issues / B-part);
//        always fully drains A(t+1) (issued last tile); vmcnt(0) at tail (t>=70).
// One barrier per tile: tile-t ds_reads retire before MFMA (lgkm dep), which precedes the barrier;
// buffer rotation is protected by the barrier itself.
// XOR swizzle on 64B rows: chunk(0..3) ^= (row ^ (row>>2)) & 3  -> <=2-way (free, m136);
// same key pre-applied to the per-lane GLOBAL source (gl16 LDS dest stays linear, rule 21).
__global__ __launch_bounds__(512, 2) void k_conv_gemm(
    const bf16_t* __restrict__ xT, const bf16_t* __restrict__ wt,
    const float* __restrict__ bias, float* __restrict__ out)
{
    __shared__ __align__(16) bf16_t As[3][256][BK];   // 48 KB
    __shared__ __align__(16) bf16_t Bs[2][384][BK];   // 48 KB

    const int tid  = threadIdx.x;
    const int lane = tid & 63;
    const int wid  = tid >> 6;
    const int wr   = wid >> 1;      // 0..3 -> co slice of 64
    const int wc   = wid & 1;       // 0..1 -> pixel slice of 112

    // bijective XCD swizzle: 896 = 8 x 112; co-fastest within chunk
    const int orig  = blockIdx.x;
    const int wgid  = (orig & 7) * 112 + (orig >> 3);
    const int co0   = (wgid & 1) * 256;
    const int sband = wgid >> 1;                 // 0..447
    const int nimg  = sband / 14;
    const int R0    = (sband - nimg * 14) * 4;   // first output row of band

    // ---- staging geometry: thread covers LDS row (tid>>2) (+128 per issue), 16B chunk tid&3
    const int trow = tid >> 2;                   // 0..127
    const int lcx  = (tid & 3) ^ ((trow ^ (trow >> 2)) & 3);   // pre-swizzled source chunk
    const bf16_t* pAsrc = wt + ((size_t)(co0 + trow) << 8) + lcx * 8;
    const size_t bandStart = (size_t)(nimg * HP + R0) * HP;    // padded-coord band origin
    const bf16_t* pBsrc = xT + (bandStart + trow) * C_IN + lcx * 8;

    auto stageA = [&](int slot, int cn, int pn) {              // 2 gl16: 256 rows x 32 ci
        const bf16_t* src = pAsrc + ((size_t)pn << 17) + (cn << 5);
        bf16_t* dst = &As[slot][0][0] + wid * 512;             // wave-uniform base (elems)
        gl16(src, dst);
        gl16(src + (128 << 8), dst + 4096);                    // +128 rows
    };
    auto stageBpart = [&](int buf, int cn, int part) {         // 1 gl16: 128 band pixels x 32 ci
        const bf16_t* src = pBsrc + ((size_t)part << 15) + (cn << 5);
        bf16_t* dst = &Bs[buf][0][0] + part * 4096 + wid * 512;
        gl16(src, dst);
    };

    // ---- fragment constants ----
    const int rl = lane & 15;
    const int kg = lane >> 4;                    // 16B chunk group 0..3 (K=32 -> 4 chunks)
    int a_off[4];
    #pragma unroll
    for (int m = 0; m < 4; m++) {
        int row = wr * 64 + m * 16 + rl;
        a_off[m] = row * BK + ((kg ^ ((row ^ (row >> 2)) & 3)) * 8);
    }
    int bpix[7];
    #pragma unroll
    for (int j = 0; j < 7; j++) {
        int nn = wc * 112 + j * 16 + rl;
        int br = nn / 56, bc = nn - br * 56;
        bpix[j] = (br + 1) * 58 + bc + 1;        // band-local padded pixel
    }

    f32x4 acc[4][7];
    #pragma unroll
    for (int m = 0; m < 4; m++)
        #pragma unroll
        for (int j = 0; j < 7; j++)
            acc[m][j] = f32x4{0.f, 0.f, 0.f, 0.f};

    // ---- prologue: B band(c=0) fully + A(t=0) + A(t=1); drain all but A(1); barrier ----
    stageBpart(0, 0, 0); stageBpart(0, 0, 1); stageBpart(0, 0, 2);
    stageA(0, 0, 0);
    stageA(1, 0, 1);
    asm volatile("s_waitcnt vmcnt(2)" ::: "memory");
    BAR();
    SCHED0();

    bf16x8 aF[4], bF[7];
    int sr = 0;                                  // A read slot = t % 3

    #pragma unroll 1
    for (int c = 0; c < 8; ++c) {
        const int bb = c & 1;
        #pragma unroll 1
        for (int p = 0; p < 9; ++p) {
            const int t = c * 9 + p;

            // ---- issue stages for tile t+2 (slot untouched by tiles t, t+1) ----
            if (t < 70) {
                int pn = p + 2, cn = c;
                if (pn >= 9) { pn -= 9; cn++; }
                int sw = sr + 2; if (sw >= 3) sw -= 3;
                stageA(sw, cn, pn);
            }
            if (c < 7 && p >= 1 && p <= 3)
                stageBpart(bb ^ 1, c + 1, p - 1);

            // ---- ds_read fragments of tile t ----
            const int q3 = p / 3;
            const int sh = (q3 - 1) * 58 + (p - q3 * 3) - 1;   // dh*58 + dw
            const bf16_t* ab = &As[sr][0][0];
            #pragma unroll
            for (int m = 0; m < 4; m++)
                aF[m] = *reinterpret_cast<const bf16x8*>(ab + a_off[m]);
            const bf16_t* bbp = &Bs[bb][0][0];
            #pragma unroll
            for (int j = 0; j < 7; j++) {
                int pix = bpix[j] + sh;
                int off = pix * BK + ((kg ^ ((pix ^ (pix >> 2)) & 3)) * 8);
                bF[j] = *reinterpret_cast<const bf16x8*>(bbp + off);
            }

            // ---- MFMA (compiler inserts lgkm waits before first use) ----
            PRIO(1);
            #pragma unroll
            for (int m = 0; m < 4; m++)
                #pragma unroll
                for (int j = 0; j < 7; j++)
                    acc[m][j] = __builtin_amdgcn_mfma_f32_16x16x32_bf16(aF[m], bF[j], acc[m][j], 0, 0, 0);
            PRIO(0);

            // ---- counted drain: keep this tile's issues in flight; A(t+1) fully landed ----
            if (t < 70)
                asm volatile("s_waitcnt vmcnt(2)" ::: "memory");
            else
                asm volatile("s_waitcnt vmcnt(0)" ::: "memory");
            BAR();
            SCHED0();
            sr++; if (sr >= 3) sr -= 3;
        }
    }

    // ---- epilogue: D row(co) = m*16 + 4*(lane>>4)+i, col(pixel) = wc*112 + j*16 + rl ----
    int hw_off[7];
    #pragma unroll
    for (int j = 0; j < 7; j++) {
        int nn = wc * 112 + j * 16 + rl;
        int br = nn / 56, bc = nn - br * 56;
        hw_off[j] = (R0 + br) * 56 + bc;
    }
    const size_t obase = (size_t)nimg * C_OUT * HW;
    #pragma unroll
    for (int m = 0; m < 4; m++) {
        int cob = co0 + wr * 64 + m * 16 + ((lane >> 4) << 2);
        #pragma unroll
        for (int i = 0; i < 4; i++) {
            int co = cob + i;
            float bv = bias[co];
            float* orow = out + obase + (size_t)co * HW;
            #pragma unroll
            for (int j = 0; j < 7; j++)
                orow[hw_off[j]] = acc[m][j][i] + bv;
        }
    }
}

extern "C" void kernel_launch(void* const* d_in, const int* in_sizes, int n_in,
                              void* d_out, int out_size, void* d_ws, size_t ws_size,
                              hipStream_t stream) {
    const float* x    = (const float*)d_in[0];
    const float* w    = (const float*)d_in[1];
    const float* bias = (const float*)d_in[2];
    float* out = (float*)d_out;

    // workspace: xT halo-padded NHWC bf16 (32*58*58*256*2 = 55.1 MB) then Wt (2.4 MB)
    bf16_t* xT = (bf16_t*)d_ws;
    bf16_t* wt = (bf16_t*)((char*)d_ws + (size_t)NB * HP * HP * C_IN * 2);

    k_halo_zero<<<dim3((NB * 228 * 32 + 255) / 256), dim3(256), 0, stream>>>(xT);
    k_x_nhwc<<<dim3(49, 4, NB), dim3(256), 0, stream>>>(x, xT);
    k_dequant<<<dim3((NQBLK + 255) / 256), dim3(256), 0, stream>>>(w, wt);
    k_conv_gemm<<<dim3(NWG), dim3(512), 0, stream>>>(xT, wt, bias, out);
}

// Round 6
// 316.303 us; speedup vs baseline: 1.1421x; 1.1421x over previous
//
#include <hip/hip_runtime.h>
#include <hip/hip_bf16.h>

typedef __bf16 bf16_t;
typedef __attribute__((ext_vector_type(8))) __bf16 bf16x8;
typedef __attribute__((ext_vector_type(4))) float f32x4;

#define C_IN   256
#define C_OUT  512
#define HW     3136      // 56*56
#define NB     32        // batch
#define HP     58        // 56 + 2 halo
#define NQBLK  36864     // (512*256*9)/32 quant blocks

// conv-GEMM: BM=256(co) x BN=224(4 img rows) x BK=64; NT=36 tiles (9 pos x 4 ci-chunks)
#define NT   36
#define NWG  896         // 448 px-bands (32 img x 14) x 2 co-blocks -> 3.5 passes (87.5% pack)

// ---- async global->LDS, 16B per lane (dest = wave-uniform base + lane*16; source per-lane) ----
typedef const __attribute__((address_space(1))) unsigned int gu32;
typedef __attribute__((address_space(3))) unsigned int lu32;
__device__ __forceinline__ void gl16(const void* g, void* l) {
    __builtin_amdgcn_global_load_lds((gu32*)g, (lu32*)l, 16, 0, 0);
}
#define BAR()    __builtin_amdgcn_s_barrier()
#define PRIO(x)  __builtin_amdgcn_s_setprio(x)
#define SCHED0() __builtin_amdgcn_sched_barrier(0)

// ---------------- kernel 1: 6-bit fake-quant + repack to Wt[p][co][ci] (bf16) ----------------
__global__ void k_dequant(const float* __restrict__ w, bf16_t* __restrict__ wt) {
    int b = blockIdx.x * blockDim.x + threadIdx.x;
    if (b >= NQBLK) return;
    const float* src = w + (size_t)b * 32;
    float v[32];
    float amax = 0.f;
    #pragma unroll
    for (int i = 0; i < 32; i += 4) {
        float4 t = *reinterpret_cast<const float4*>(src + i);
        v[i] = t.x; v[i+1] = t.y; v[i+2] = t.z; v[i+3] = t.w;
        amax = fmaxf(amax, fmaxf(fmaxf(fabsf(t.x), fabsf(t.y)),
                                 fmaxf(fabsf(t.z), fabsf(t.w))));
    }
    float scale = amax / 31.0f;
    if (scale == 0.f) scale = 1.f;
    #pragma unroll
    for (int i = 0; i < 32; i++) {
        float q = rintf(v[i] / scale);            // jnp.round = RNE = rintf
        q = fminf(31.f, fmaxf(-32.f, q));
        float dq = q * scale;
        int flat = b * 32 + i;                    // flat over OIHW
        int p    = flat % 9;
        int rest = flat / 9;
        int ci   = rest & 255;
        int co   = rest >> 8;
        wt[((size_t)(p * C_OUT + co) << 8) + ci] = (bf16_t)dq;
    }
}

// ---------------- kernel 1b: zero the 1-pixel halo ring of xT ----------------
__global__ void k_halo_zero(bf16_t* __restrict__ xT) {
    int idx = blockIdx.x * 256 + threadIdx.x;
    if (idx >= NB * 228 * 32) return;
    int c8 = idx & 31;
    int t  = idx >> 5;
    int p  = t % 228;
    int n  = t / 228;
    int hh, ww;
    if      (p < 58)  { hh = 0;           ww = p; }
    else if (p < 116) { hh = 57;          ww = p - 58; }
    else if (p < 172) { hh = p - 116 + 1; ww = 0; }
    else              { hh = p - 172 + 1; ww = 57; }
    size_t e = (((size_t)n * HP + hh) * HP + ww) * C_IN + c8 * 8;
    *reinterpret_cast<uint4*>(xT + e) = make_uint4(0, 0, 0, 0);
}

// ------- kernel 2: x NCHW fp32 -> halo-padded NHWC bf16 (xT[n][58][58][ci]) -------
__global__ void k_x_nhwc(const float* __restrict__ x, bf16_t* __restrict__ xT) {
    __shared__ float tile[64][65];
    const int n   = blockIdx.z;
    const int cb  = blockIdx.y * 64;
    const int hwb = blockIdx.x * 64;
    const int t   = threadIdx.x;

    const int col = t & 63;
    const int r0  = t >> 6;
    #pragma unroll
    for (int k = 0; k < 16; k++) {
        int r = r0 * 16 + k;
        tile[r][col] = x[((size_t)(n * C_IN + cb + r)) * HW + hwb + col];
    }
    __syncthreads();

    const int j  = t >> 2;
    const int co = (t & 3) * 16;
    const int hw = hwb + j;
    const int hh = hw / 56, ww = hw - hh * 56;
    __align__(16) bf16_t vals[16];
    #pragma unroll
    for (int k = 0; k < 16; k++)
        vals[k] = (bf16_t)tile[co + k][j];
    bf16_t* dst = xT + (((size_t)n * HP + hh + 1) * HP + (ww + 1)) * C_IN + cb + co;
    *reinterpret_cast<uint4*>(dst)     = *reinterpret_cast<uint4*>(&vals[0]);
    *reinterpret_cast<uint4*>(dst + 8) = *reinterpret_cast<uint4*>(&vals[8]);
}

// ---------------- kernel 3: implicit-GEMM conv, 256x224 4-phase deep pipeline ----------------
// 8 waves as 4(M) x 2(N): wave = 64(co) x 112(px), acc[4][7]; K-tile = 64 ci of one position.
// LDS: As[2][256][64] (64KB) + Bs[2][224][64] (56KB) = 120KB; rows = 128B, XOR swizzle
//   chunk(0..7) ^= row&7 on ds_read, same key pre-applied to per-lane GLOBAL source (R3: 0 conflicts).
// B tile = the SHIFTED 224-px block (shift applied at staging source from halo-padded xT),
//   so all ds_read addresses are tile-invariant constants.
// Ledger (buf(t)=t&1; A reads happen ONLY in P1):
//   B-lo(t+1)@t.P1, B-hi(t+1)@t.P2 -> buf(t^1), not read during t: safe.
//   A-full(t+2)@t.P4 -> buf(t) A-region; its reads finished at t.P1: safe.
//   vmcnt(4) at t.P4 end: leaves A(t+2)'s 4 issues in flight; drains A(t+1) (issued 4 phases ago)
//   and B(t+1) (2-3 phases ago) => tile t+1 fully landed before its P1. Tail (t>=34): vmcnt(0).
__global__ __launch_bounds__(512, 2) void k_conv_gemm(
    const bf16_t* __restrict__ xT, const bf16_t* __restrict__ wt,
    const float* __restrict__ bias, float* __restrict__ out)
{
    __shared__ __align__(16) bf16_t As[2][256][64];   // 64 KB
    __shared__ __align__(16) bf16_t Bs[2][224][64];   // 56 KB

    const int tid  = threadIdx.x;
    const int lane = tid & 63;
    const int wid  = tid >> 6;
    const int wr   = wid >> 1;      // 0..3 -> co slice of 64
    const int wc   = wid & 1;       // 0..1 -> px slice of 112

    // bijective XCD swizzle: 896 = 8 x 112; co-fastest within chunk
    const int orig  = blockIdx.x;
    const int wgid  = (orig & 7) * 112 + (orig >> 3);
    const int co0   = (wgid & 1) * 256;
    const int sband = wgid >> 1;                 // 0..447
    const int nimg  = sband / 14;
    const int R0    = (sband - nimg * 14) * 4;   // first output row of band (4 rows/band)

    // ---- staging geometry: 512 threads cover 64 rows x 64 ci per issue; thread row tid>>3, chunk tid&7
    const int trow = tid >> 3;                   // 0..63
    const int lcx  = (tid & 7) ^ (trow & 7);     // pre-swizzled source chunk (key = row&7)

    const bf16_t* pA[4];
    const bf16_t* pB[4];
    #pragma unroll
    for (int i = 0; i < 4; i++) {
        pA[i] = wt + ((size_t)(co0 + i * 64 + trow) << 8) + lcx * 8;
        int r  = i * 64 + trow;                  // output px in band (i=3 used only for r<224)
        int br = r / 56, bc = r - br * 56;
        pB[i] = xT + (((size_t)nimg * HP + R0 + br + 1) * HP + (bc + 1)) * C_IN + lcx * 8;
    }

    // stageA: full 256x64 A-tile of K-tile tk (4 gl16/thread)
    auto stageA = [&](int buf, int tk) {
        const size_t off = ((size_t)(tk >> 2) << 17) + ((tk & 3) << 6);
        bf16_t* dst = &As[buf][0][0] + wid * 512;
        #pragma unroll
        for (int i = 0; i < 4; i++)
            gl16(pA[i] + off, dst + i * 4096);
    };
    // stageB half: half 0 = rows 0-127 (2 issues), half 1 = rows 128-223 (1 + partial)
    auto stageB = [&](int buf, int tk, int half) {
        const int p  = tk >> 2;
        const int q3 = p / 3;
        const int off = ((q3 - 1) * HP + (p - q3 * 3) - 1) * C_IN + ((tk & 3) << 6);
        bf16_t* dst = &Bs[buf][0][0] + wid * 512;
        if (half == 0) {
            gl16(pB[0] + off, dst);
            gl16(pB[1] + off, dst + 4096);
        } else {
            gl16(pB[2] + off, dst + 8192);
            if (tid < 256)                        // rows 192-223 (waves 0-3)
                gl16(pB[3] + off, dst + 12288);
        }
    };

    // ---- tile-invariant fragment read offsets (elements), swizzled chunk = (ks*4+kg) ^ (row&7)
    const int rl = lane & 15;
    const int kg = lane >> 4;
    int a_off[4][2], b_off[7][2];
    #pragma unroll
    for (int m = 0; m < 4; m++) {
        int row = wr * 64 + m * 16 + rl;
        a_off[m][0] = row * 64 + ((kg       ^ (row & 7)) * 8);
        a_off[m][1] = row * 64 + (((4 + kg) ^ (row & 7)) * 8);
    }
    #pragma unroll
    for (int j = 0; j < 7; j++) {
        int row = wc * 112 + j * 16 + rl;
        b_off[j][0] = row * 64 + ((kg       ^ (row & 7)) * 8);
        b_off[j][1] = row * 64 + (((4 + kg) ^ (row & 7)) * 8);
    }

    f32x4 acc[4][7];
    #pragma unroll
    for (int m = 0; m < 4; m++)
        #pragma unroll
        for (int j = 0; j < 7; j++)
            acc[m][j] = f32x4{0.f, 0.f, 0.f, 0.f};

    // ---- prologue: A(0), B(0), A(1); vmcnt(4) leaves A(1) in flight, tile0 landed ----
    stageA(0, 0);
    stageB(0, 0, 0); stageB(0, 0, 1);
    stageA(1, 1);
    asm volatile("s_waitcnt vmcnt(4)" ::: "memory");
    BAR();
    SCHED0();

    bf16x8 aF[4][2], bF[2][2];

    #pragma unroll 1
    for (int t = 0; t < NT; ++t) {
        const int cur = t & 1;
        const bf16_t* ab = &As[cur][0][0];
        const bf16_t* bb = &Bs[cur][0][0];

        // ======== P1: read A(m0-3, both k) [8] + B(j0-1) [4]; stage B-lo(t+1); MFMA j0-1
        #pragma unroll
        for (int m = 0; m < 4; m++) {
            aF[m][0] = *reinterpret_cast<const bf16x8*>(ab + a_off[m][0]);
            aF[m][1] = *reinterpret_cast<const bf16x8*>(ab + a_off[m][1]);
        }
        #pragma unroll
        for (int j = 0; j < 2; j++) {
            bF[j][0] = *reinterpret_cast<const bf16x8*>(bb + b_off[j][0]);
            bF[j][1] = *reinterpret_cast<const bf16x8*>(bb + b_off[j][1]);
        }
        if (t + 1 < NT) stageB(cur ^ 1, t + 1, 0);
        BAR();
        asm volatile("s_waitcnt lgkmcnt(0)" ::: "memory");
        SCHED0();
        PRIO(1);
        #pragma unroll
        for (int m = 0; m < 4; m++)
            #pragma unroll
            for (int j = 0; j < 2; j++) {
                acc[m][j] = __builtin_amdgcn_mfma_f32_16x16x32_bf16(aF[m][0], bF[j][0], acc[m][j], 0, 0, 0);
                acc[m][j] = __builtin_amdgcn_mfma_f32_16x16x32_bf16(aF[m][1], bF[j][1], acc[m][j], 0, 0, 0);
            }
        PRIO(0);
        BAR();

        // ======== P2: read B(j2-3) [4]; stage B-hi(t+1); MFMA j2-3
        #pragma unroll
        for (int j = 0; j < 2; j++) {
            bF[j][0] = *reinterpret_cast<const bf16x8*>(bb + b_off[j + 2][0]);
            bF[j][1] = *reinterpret_cast<const bf16x8*>(bb + b_off[j + 2][1]);
        }
        if (t + 1 < NT) stageB(cur ^ 1, t + 1, 1);
        BAR();
        asm volatile("s_waitcnt lgkmcnt(0)" ::: "memory");
        SCHED0();
        PRIO(1);
        #pragma unroll
        for (int m = 0; m < 4; m++)
            #pragma unroll
            for (int j = 0; j < 2; j++) {
                acc[m][j + 2] = __builtin_amdgcn_mfma_f32_16x16x32_bf16(aF[m][0], bF[j][0], acc[m][j + 2], 0, 0, 0);
                acc[m][j + 2] = __builtin_amdgcn_mfma_f32_16x16x32_bf16(aF[m][1], bF[j][1], acc[m][j + 2], 0, 0, 0);
            }
        PRIO(0);
        BAR();

        // ======== P3: read B(j4-5) [4]; no stage; MFMA j4-5
        #pragma unroll
        for (int j = 0; j < 2; j++) {
            bF[j][0] = *reinterpret_cast<const bf16x8*>(bb + b_off[j + 4][0]);
            bF[j][1] = *reinterpret_cast<const bf16x8*>(bb + b_off[j + 4][1]);
        }
        BAR();
        asm volatile("s_waitcnt lgkmcnt(0)" ::: "memory");
        SCHED0();
        PRIO(1);
        #pragma unroll
        for (int m = 0; m < 4; m++)
            #pragma unroll
            for (int j = 0; j < 2; j++) {
                acc[m][j + 4] = __builtin_amdgcn_mfma_f32_16x16x32_bf16(aF[m][0], bF[j][0], acc[m][j + 4], 0, 0, 0);
                acc[m][j + 4] = __builtin_amdgcn_mfma_f32_16x16x32_bf16(aF[m][1], bF[j][1], acc[m][j + 4], 0, 0, 0);
            }
        PRIO(0);
        BAR();

        // ======== P4: read B(j6) [2]; stage A-full(t+2) into buf(t); MFMA j6; counted drain
        bF[0][0] = *reinterpret_cast<const bf16x8*>(bb + b_off[6][0]);
        bF[0][1] = *reinterpret_cast<const bf16x8*>(bb + b_off[6][1]);
        if (t + 2 < NT) stageA(cur, t + 2);
        BAR();
        asm volatile("s_waitcnt lgkmcnt(0)" ::: "memory");
        SCHED0();
        PRIO(1);
        #pragma unroll
        for (int m = 0; m < 4; m++) {
            acc[m][6] = __builtin_amdgcn_mfma_f32_16x16x32_bf16(aF[m][0], bF[0][0], acc[m][6], 0, 0, 0);
            acc[m][6] = __builtin_amdgcn_mfma_f32_16x16x32_bf16(aF[m][1], bF[0][1], acc[m][6], 0, 0, 0);
        }
        PRIO(0);
        if (t + 2 < NT)
            asm volatile("s_waitcnt vmcnt(4)" ::: "memory");   // tile t+1 fully landed; A(t+2) in flight
        else
            asm volatile("s_waitcnt vmcnt(0)" ::: "memory");   // tail drain
        BAR();
        SCHED0();
    }

    // ---- epilogue: D row(co) = m*16 + 4*(lane>>4)+i, col(px) = wc*112 + j*16 + rl ----
    int hw_off[7];
    #pragma unroll
    for (int j = 0; j < 7; j++) {
        int nn = wc * 112 + j * 16 + rl;
        int br = nn / 56, bc = nn - br * 56;
        hw_off[j] = (R0 + br) * 56 + bc;
    }
    const size_t obase = (size_t)nimg * C_OUT * HW;
    #pragma unroll
    for (int m = 0; m < 4; m++) {
        int cob = co0 + wr * 64 + m * 16 + ((lane >> 4) << 2);
        #pragma unroll
        for (int i = 0; i < 4; i++) {
            int co = cob + i;
            float bv = bias[co];
            float* orow = out + obase + (size_t)co * HW;
            #pragma unroll
            for (int j = 0; j < 7; j++)
                orow[hw_off[j]] = acc[m][j][i] + bv;
        }
    }
}

extern "C" void kernel_launch(void* const* d_in, const int* in_sizes, int n_in,
                              void* d_out, int out_size, void* d_ws, size_t ws_size,
                              hipStream_t stream) {
    const float* x    = (const float*)d_in[0];
    const float* w    = (const float*)d_in[1];
    const float* bias = (const float*)d_in[2];
    float* out = (float*)d_out;

    // workspace: xT halo-padded NHWC bf16 (32*58*58*256*2 = 55.1 MB) then Wt (2.4 MB)
    bf16_t* xT = (bf16_t*)d_ws;
    bf16_t* wt = (bf16_t*)((char*)d_ws + (size_t)NB * HP * HP * C_IN * 2);

    k_halo_zero<<<dim3((NB * 228 * 32 + 255) / 256), dim3(256), 0, stream>>>(xT);
    k_x_nhwc<<<dim3(49, 4, NB), dim3(256), 0, stream>>>(x, xT);
    k_dequant<<<dim3((NQBLK + 255) / 256), dim3(256), 0, stream>>>(w, wt);
    k_conv_gemm<<<dim3(NWG), dim3(512), 0, stream>>>(xT, wt, bias, out);
}

// Round 7
// 312.666 us; speedup vs baseline: 1.1554x; 1.0116x over previous
//
#include <hip/hip_runtime.h>
#include <hip/hip_bf16.h>

typedef __bf16 bf16_t;
typedef __attribute__((ext_vector_type(8))) __bf16 bf16x8;
typedef __attribute__((ext_vector_type(4))) float f32x4;

#define C_IN   256
#define C_OUT  512
#define HW     3136      // 56*56
#define NB     32        // batch
#define HP     58        // 56 + 2 halo
#define NQBLK  36864     // (512*256*9)/32 quant blocks

// conv-GEMM: BM=128(co) x BN=128(px) x BK=64; NT=36 tiles (9 pos x 4 ci-chunks)
#define NT   36
#define NWG  3136        // 784 px-blocks x 4 co-blocks -> 6.125 passes of 512 blocks (2/CU)

// ---- async global->LDS, 16B per lane (dest = wave-uniform base + lane*16; source per-lane) ----
typedef const __attribute__((address_space(1))) unsigned int gu32;
typedef __attribute__((address_space(3))) unsigned int lu32;
__device__ __forceinline__ void gl16(const void* g, void* l) {
    __builtin_amdgcn_global_load_lds((gu32*)g, (lu32*)l, 16, 0, 0);
}
#define BAR()    __builtin_amdgcn_s_barrier()
#define PRIO(x)  __builtin_amdgcn_s_setprio(x)
#define SCHED0() __builtin_amdgcn_sched_barrier(0)

// ---------------- kernel 1: 6-bit fake-quant + repack to Wt[p][co][ci] (bf16) ----------------
__global__ void k_dequant(const float* __restrict__ w, bf16_t* __restrict__ wt) {
    int b = blockIdx.x * blockDim.x + threadIdx.x;
    if (b >= NQBLK) return;
    const float* src = w + (size_t)b * 32;
    float v[32];
    float amax = 0.f;
    #pragma unroll
    for (int i = 0; i < 32; i += 4) {
        float4 t = *reinterpret_cast<const float4*>(src + i);
        v[i] = t.x; v[i+1] = t.y; v[i+2] = t.z; v[i+3] = t.w;
        amax = fmaxf(amax, fmaxf(fmaxf(fabsf(t.x), fabsf(t.y)),
                                 fmaxf(fabsf(t.z), fabsf(t.w))));
    }
    float scale = amax / 31.0f;
    if (scale == 0.f) scale = 1.f;
    #pragma unroll
    for (int i = 0; i < 32; i++) {
        float q = rintf(v[i] / scale);            // jnp.round = RNE = rintf
        q = fminf(31.f, fmaxf(-32.f, q));
        float dq = q * scale;
        int flat = b * 32 + i;                    // flat over OIHW
        int p    = flat % 9;
        int rest = flat / 9;
        int ci   = rest & 255;
        int co   = rest >> 8;
        wt[((size_t)(p * C_OUT + co) << 8) + ci] = (bf16_t)dq;
    }
}

// ---------------- kernel 1b: zero the 1-pixel halo ring of xT ----------------
__global__ void k_halo_zero(bf16_t* __restrict__ xT) {
    int idx = blockIdx.x * 256 + threadIdx.x;
    if (idx >= NB * 228 * 32) return;
    int c8 = idx & 31;
    int t  = idx >> 5;
    int p  = t % 228;
    int n  = t / 228;
    int hh, ww;
    if      (p < 58)  { hh = 0;           ww = p; }
    else if (p < 116) { hh = 57;          ww = p - 58; }
    else if (p < 172) { hh = p - 116 + 1; ww = 0; }
    else              { hh = p - 172 + 1; ww = 57; }
    size_t e = (((size_t)n * HP + hh) * HP + ww) * C_IN + c8 * 8;
    *reinterpret_cast<uint4*>(xT + e) = make_uint4(0, 0, 0, 0);
}

// ------- kernel 2: x NCHW fp32 -> halo-padded NHWC bf16 (xT[n][58][58][ci]) -------
__global__ void k_x_nhwc(const float* __restrict__ x, bf16_t* __restrict__ xT) {
    __shared__ float tile[64][65];
    const int n   = blockIdx.z;
    const int cb  = blockIdx.y * 64;
    const int hwb = blockIdx.x * 64;
    const int t   = threadIdx.x;

    const int col = t & 63;
    const int r0  = t >> 6;
    #pragma unroll
    for (int k = 0; k < 16; k++) {
        int r = r0 * 16 + k;
        tile[r][col] = x[((size_t)(n * C_IN + cb + r)) * HW + hwb + col];
    }
    __syncthreads();

    const int j  = t >> 2;
    const int co = (t & 3) * 16;
    const int hw = hwb + j;
    const int hh = hw / 56, ww = hw - hh * 56;
    __align__(16) bf16_t vals[16];
    #pragma unroll
    for (int k = 0; k < 16; k++)
        vals[k] = (bf16_t)tile[co + k][j];
    bf16_t* dst = xT + (((size_t)n * HP + hh + 1) * HP + (ww + 1)) * C_IN + cb + co;
    *reinterpret_cast<uint4*>(dst)     = *reinterpret_cast<uint4*>(&vals[0]);
    *reinterpret_cast<uint4*>(dst + 8) = *reinterpret_cast<uint4*>(&vals[8]);
}

// ---------------- kernel 3: implicit-GEMM conv, 128x128 occupancy-first ----------------
// 256 threads = 4 waves as 2(M) x 2(N); wave tile = 64(co) x 64(px); acc[4][4] f32x4 = 64 VGPR.
// LDS: As[2][128][64] + Bs[2][128][64] bf16 = 64 KB  ->  2 blocks/CU (128 KB), 16 waves/CU.
// The two co-resident blocks hit barriers at uncorrelated times: one block's MFMA phase
// covers the other's LDS-read/stage/barrier phases (the overlap 5 rounds of intra-block
// scheduling could not produce at 2 waves/SIMD).
// Per tile: {issue stage(t+1) -> buf^1; ds_read 16 b128 (2 k-slices); 32 MFMA; vmcnt(0); BAR}.
// XOR swizzle chunk(0..7) ^= row&7 on 128-B rows (R3/R6-proven: 0 conflicts); pre-swizzled
// per-lane GLOBAL source, linear gl16 LDS dest (rule 21).
__global__ __launch_bounds__(256, 4) void k_conv_gemm(
    const bf16_t* __restrict__ xT, const bf16_t* __restrict__ wt,
    const float* __restrict__ bias, float* __restrict__ out)
{
    __shared__ __align__(16) bf16_t As[2][128][64];   // 32 KB
    __shared__ __align__(16) bf16_t Bs[2][128][64];   // 32 KB

    const int tid  = threadIdx.x;
    const int lane = tid & 63;
    const int wid  = tid >> 6;      // 0..3
    const int wr   = wid >> 1;      // co slice of 64
    const int wc   = wid & 1;       // px slice of 64

    // bijective XCD swizzle: 3136 = 8 x 392; co-fastest within an XCD chunk
    const int orig = blockIdx.x;
    const int wgid = (orig & 7) * 392 + (orig >> 3);
    const int co0  = (wgid & 3) * 128;
    const int s0   = (wgid >> 2) * 128;

    // ---- staging geometry: thread covers row i*32 + (tid>>3), 16B chunk tid&7, per issue i
    const int trow = tid >> 3;                   // 0..31
    const int lcx  = (tid & 7) ^ (trow & 7);     // pre-swizzled source chunk (key = row&7)

    int aoff[4], boff[4];                        // element offsets (fit 32-bit)
    #pragma unroll
    for (int i = 0; i < 4; i++) {
        aoff[i] = ((co0 + i * 32 + trow) << 8) + lcx * 8;
        int px = s0 + i * 32 + trow;
        int n  = px / HW;
        int hw = px - n * HW;
        int hh = hw / 56, ww = hw - hh * 56;
        boff[i] = ((n * HP + hh + 1) * HP + ww + 1) * C_IN + lcx * 8;
    }

    auto stage = [&](int buf, int tk) {
        const int p  = tk >> 2;
        const int kc = (tk & 3) << 6;
        const size_t aT = (size_t)p * (C_OUT << 8) + kc;
        const int q3 = p / 3;
        const int bT = ((q3 - 1) * HP + (p - q3 * 3) - 1) * C_IN + kc;
        bf16_t* dA = &As[buf][0][0] + wid * 512;
        bf16_t* dB = &Bs[buf][0][0] + wid * 512;
        #pragma unroll
        for (int i = 0; i < 4; i++)
            gl16(wt + aoff[i] + aT, dA + i * 2048);
        #pragma unroll
        for (int i = 0; i < 4; i++)
            gl16(xT + boff[i] + bT, dB + i * 2048);
    };

    // ---- tile-invariant fragment read offsets (elements); swizzle key = rl&7 ----
    const int rl = lane & 15;
    const int kg = lane >> 4;
    int a_off[4][2], b_off[4][2];
    #pragma unroll
    for (int m = 0; m < 4; m++) {
        int row = wr * 64 + m * 16 + rl;
        a_off[m][0] = row * 64 + ((kg       ^ (rl & 7)) * 8);
        a_off[m][1] = row * 64 + (((4 + kg) ^ (rl & 7)) * 8);
    }
    #pragma unroll
    for (int j = 0; j < 4; j++) {
        int row = wc * 64 + j * 16 + rl;
        b_off[j][0] = row * 64 + ((kg       ^ (rl & 7)) * 8);
        b_off[j][1] = row * 64 + (((4 + kg) ^ (rl & 7)) * 8);
    }

    f32x4 acc[4][4];
    #pragma unroll
    for (int m = 0; m < 4; m++)
        #pragma unroll
        for (int j = 0; j < 4; j++)
            acc[m][j] = f32x4{0.f, 0.f, 0.f, 0.f};

    // ---- prologue ----
    stage(0, 0);
    asm volatile("s_waitcnt vmcnt(0)" ::: "memory");
    BAR();
    SCHED0();

    #pragma unroll 1
    for (int t = 0; t < NT; ++t) {
        const int cur = t & 1;
        if (t + 1 < NT) stage(cur ^ 1, t + 1);   // issue first: whole tile to land

        const bf16_t* ab = &As[cur][0][0];
        const bf16_t* bb = &Bs[cur][0][0];

        // k-slice 0 (keeps <=8 fragments live for the 128-VGPR budget)
        {
            bf16x8 aF[4], bF[4];
            #pragma unroll
            for (int m = 0; m < 4; m++)
                aF[m] = *reinterpret_cast<const bf16x8*>(ab + a_off[m][0]);
            #pragma unroll
            for (int j = 0; j < 4; j++)
                bF[j] = *reinterpret_cast<const bf16x8*>(bb + b_off[j][0]);
            PRIO(1);
            #pragma unroll
            for (int m = 0; m < 4; m++)
                #pragma unroll
                for (int j = 0; j < 4; j++)
                    acc[m][j] = __builtin_amdgcn_mfma_f32_16x16x32_bf16(aF[m], bF[j], acc[m][j], 0, 0, 0);
            PRIO(0);
        }
        // k-slice 1
        {
            bf16x8 aF[4], bF[4];
            #pragma unroll
            for (int m = 0; m < 4; m++)
                aF[m] = *reinterpret_cast<const bf16x8*>(ab + a_off[m][1]);
            #pragma unroll
            for (int j = 0; j < 4; j++)
                bF[j] = *reinterpret_cast<const bf16x8*>(bb + b_off[j][1]);
            PRIO(1);
            #pragma unroll
            for (int m = 0; m < 4; m++)
                #pragma unroll
                for (int j = 0; j < 4; j++)
                    acc[m][j] = __builtin_amdgcn_mfma_f32_16x16x32_bf16(aF[m], bF[j], acc[m][j], 0, 0, 0);
            PRIO(0);
        }

        asm volatile("s_waitcnt vmcnt(0)" ::: "memory");   // t+1 fully in LDS
        BAR();                                             // release buf^1 to readers, buf to writers
        SCHED0();
    }

    // ---- epilogue: D row(co) = m*16 + 4*(lane>>4)+i, col(px) = wc*64 + j*16 + rl ----
    int pxn[4], pxhw[4];
    #pragma unroll
    for (int j = 0; j < 4; j++) {
        int px = s0 + wc * 64 + j * 16 + rl;
        pxn[j]  = px / HW;
        pxhw[j] = px - pxn[j] * HW;
    }
    #pragma unroll
    for (int m = 0; m < 4; m++) {
        int cob = co0 + wr * 64 + m * 16 + ((lane >> 4) << 2);
        #pragma unroll
        for (int i = 0; i < 4; i++) {
            int co = cob + i;
            float bv = bias[co];
            #pragma unroll
            for (int j = 0; j < 4; j++)
                out[((size_t)(pxn[j] * C_OUT + co)) * HW + pxhw[j]] = acc[m][j][i] + bv;
        }
    }
}

extern "C" void kernel_launch(void* const* d_in, const int* in_sizes, int n_in,
                              void* d_out, int out_size, void* d_ws, size_t ws_size,
                              hipStream_t stream) {
    const float* x    = (const float*)d_in[0];
    const float* w    = (const float*)d_in[1];
    const float* bias = (const float*)d_in[2];
    float* out = (float*)d_out;

    // workspace: xT halo-padded NHWC bf16 (32*58*58*256*2 = 55.1 MB) then Wt (2.4 MB)
    bf16_t* xT = (bf16_t*)d_ws;
    bf16_t* wt = (bf16_t*)((char*)d_ws + (size_t)NB * HP * HP * C_IN * 2);

    k_halo_zero<<<dim3((NB * 228 * 32 + 255) / 256), dim3(256), 0, stream>>>(xT);
    k_x_nhwc<<<dim3(49, 4, NB), dim3(256), 0, stream>>>(x, xT);
    k_dequant<<<dim3((NQBLK + 255) / 256), dim3(256), 0, stream>>>(w, wt);
    k_conv_gemm<<<dim3(NWG), dim3(256), 0, stream>>>(xT, wt, bias, out);
}

// Round 8
// 276.073 us; speedup vs baseline: 1.3085x; 1.1326x over previous
//
#include <hip/hip_runtime.h>
#include <hip/hip_bf16.h>

typedef __bf16 bf16_t;
typedef __attribute__((ext_vector_type(8))) __bf16 bf16x8;
typedef __attribute__((ext_vector_type(4))) float f32x4;
typedef __attribute__((ext_vector_type(4))) int   i32x4;

#define C_IN   256
#define C_OUT  512
#define HW     3136      // 56*56
#define NB     32        // batch
#define HP     58        // 56 + 2 halo
#define NQBLK  36864     // (512*256*9)/32 quant blocks

// conv-GEMM: BM=256(co) x BN=224(4 img rows) x BK=64; NT=36 tiles (9 pos x 4 ci-chunks)
#define NT   36
#define NWG  896         // 448 px-bands (32 img x 14) x 2 co-blocks

typedef const __attribute__((address_space(1))) unsigned int gu32;
typedef __attribute__((address_space(3))) unsigned int lu32;
__device__ __forceinline__ void gl16(const void* g, void* l) {
    __builtin_amdgcn_global_load_lds((gu32*)g, (lu32*)l, 16, 0, 0);
}
#define BAR()    __builtin_amdgcn_s_barrier()
#define PRIO(x)  __builtin_amdgcn_s_setprio(x)
#define SCHED0() __builtin_amdgcn_sched_barrier(0)

__device__ __forceinline__ bf16x8 asbf(i32x4 v) {
    union { i32x4 a; bf16x8 b; } u; u.a = v; return u.b;
}
__device__ __forceinline__ f32x4 MF(i32x4 a, i32x4 b, f32x4 c) {
    return __builtin_amdgcn_mfma_f32_16x16x32_bf16(asbf(a), asbf(b), c, 0, 0, 0);
}

// ---------------- kernel 1: 6-bit fake-quant + repack to Wt[p][co][ci] (bf16) ----------------
__global__ void k_dequant(const float* __restrict__ w, bf16_t* __restrict__ wt) {
    int b = blockIdx.x * blockDim.x + threadIdx.x;
    if (b >= NQBLK) return;
    const float* src = w + (size_t)b * 32;
    float v[32];
    float amax = 0.f;
    #pragma unroll
    for (int i = 0; i < 32; i += 4) {
        float4 t = *reinterpret_cast<const float4*>(src + i);
        v[i] = t.x; v[i+1] = t.y; v[i+2] = t.z; v[i+3] = t.w;
        amax = fmaxf(amax, fmaxf(fmaxf(fabsf(t.x), fabsf(t.y)),
                                 fmaxf(fabsf(t.z), fabsf(t.w))));
    }
    float scale = amax / 31.0f;
    if (scale == 0.f) scale = 1.f;
    #pragma unroll
    for (int i = 0; i < 32; i++) {
        float q = rintf(v[i] / scale);            // jnp.round = RNE = rintf
        q = fminf(31.f, fmaxf(-32.f, q));
        float dq = q * scale;
        int flat = b * 32 + i;                    // flat over OIHW
        int p    = flat % 9;
        int rest = flat / 9;
        int ci   = rest & 255;
        int co   = rest >> 8;
        wt[((size_t)(p * C_OUT + co) << 8) + ci] = (bf16_t)dq;
    }
}

// ---------------- kernel 1b: zero the 1-pixel halo ring of xT ----------------
__global__ void k_halo_zero(bf16_t* __restrict__ xT) {
    int idx = blockIdx.x * 256 + threadIdx.x;
    if (idx >= NB * 228 * 32) return;
    int c8 = idx & 31;
    int t  = idx >> 5;
    int p  = t % 228;
    int n  = t / 228;
    int hh, ww;
    if      (p < 58)  { hh = 0;           ww = p; }
    else if (p < 116) { hh = 57;          ww = p - 58; }
    else if (p < 172) { hh = p - 116 + 1; ww = 0; }
    else              { hh = p - 172 + 1; ww = 57; }
    size_t e = (((size_t)n * HP + hh) * HP + ww) * C_IN + c8 * 8;
    *reinterpret_cast<uint4*>(xT + e) = make_uint4(0, 0, 0, 0);
}

// ------- kernel 2: x NCHW fp32 -> halo-padded NHWC bf16 (xT[n][58][58][ci]) -------
__global__ void k_x_nhwc(const float* __restrict__ x, bf16_t* __restrict__ xT) {
    __shared__ float tile[64][65];
    const int n   = blockIdx.z;
    const int cb  = blockIdx.y * 64;
    const int hwb = blockIdx.x * 64;
    const int t   = threadIdx.x;

    const int col = t & 63;
    const int r0  = t >> 6;
    #pragma unroll
    for (int k = 0; k < 16; k++) {
        int r = r0 * 16 + k;
        tile[r][col] = x[((size_t)(n * C_IN + cb + r)) * HW + hwb + col];
    }
    __syncthreads();

    const int j  = t >> 2;
    const int co = (t & 3) * 16;
    const int hw = hwb + j;
    const int hh = hw / 56, ww = hw - hh * 56;
    __align__(16) bf16_t vals[16];
    #pragma unroll
    for (int k = 0; k < 16; k++)
        vals[k] = (bf16_t)tile[co + k][j];
    bf16_t* dst = xT + (((size_t)n * HP + hh + 1) * HP + (ww + 1)) * C_IN + cb + co;
    *reinterpret_cast<uint4*>(dst)     = *reinterpret_cast<uint4*>(&vals[0]);
    *reinterpret_cast<uint4*>(dst + 8) = *reinterpret_cast<uint4*>(&vals[8]);
}

// ------------- kernel 3: implicit-GEMM conv, within-wave pipelined (counted lgkmcnt) -------------
// Geometry = R6: 8 waves 4(M)x2(N), wave 64(co)x112(px), acc[4][7]; K-tile = 64 ci of one position.
// LDS: As[3][256][64] (96KB, TRIPLE: A(t) read, A(t+1) landed, A(t+2) in flight)
//      Bs[2][224][64] (56KB double)  -> 152 KB, 1 block/CU.
// Tile body = 7 j-groups of 8 MFMA. B-frags flow through a 3-slot register pipeline:
//   group j: issue ds_read bF[j+2]; s_waitcnt lgkmcnt(4) (drains bF[j], keeps j+1,j+2);
//   sched_barrier(0) [rule 18]; MFMA group j.  A-frags (8 reads) once per tile.
//   -> each wave's ds_reads overlap its OWN MFMAs; no per-phase barriers at all.
// Stage ledger: B(t+1) issued at j0/j1 (into Bs[(t+1)&1], not read during t);
//   A(t+2) at j3/j5 (into slot (t+2)%3, untouched by t,t+1). End of tile: vmcnt(4)
//   keeps A(t+2)'s 4 newest in flight, drains A(t+1)+B(t+1) (1-1.5 tiles of latency given).
//   One barrier per tile. Tail: vmcnt(0) when no A(t+2).
// XOR swizzle chunk(0..7) ^= row&7 on 128B rows (R3/R6: 0 conflicts); key row&7 == rl&7
//   (j,m row steps are multiples of 16); pre-swizzled per-lane global source, linear gl16 dest.
__global__ __launch_bounds__(512, 2) void k_conv_gemm(
    const bf16_t* __restrict__ xT, const bf16_t* __restrict__ wt,
    const float* __restrict__ bias, float* __restrict__ out)
{
    __shared__ __align__(16) bf16_t As[3][256][64];   // 96 KB
    __shared__ __align__(16) bf16_t Bs[2][224][64];   // 56 KB

    const int tid  = threadIdx.x;
    const int lane = tid & 63;
    const int wid  = tid >> 6;
    const int wr   = wid >> 1;      // 0..3 -> co slice of 64
    const int wc   = wid & 1;       // 0..1 -> px slice of 112

    // bijective XCD swizzle: 896 = 8 x 112; co-fastest within chunk
    const int orig  = blockIdx.x;
    const int wgid  = (orig & 7) * 112 + (orig >> 3);
    const int co0   = (wgid & 1) * 256;
    const int sband = wgid >> 1;                 // 0..447
    const int nimg  = sband / 14;
    const int R0    = (sband - nimg * 14) * 4;   // first output row of band

    // ---- staging geometry: per 64-row issue, thread covers row tid>>3, 16B chunk tid&7
    const int trow = tid >> 3;                   // 0..63
    const int lcx  = (tid & 7) ^ (trow & 7);     // pre-swizzled source chunk (key = row&7)

    const bf16_t* pA[4];
    const bf16_t* pB[4];
    #pragma unroll
    for (int i = 0; i < 4; i++) {
        pA[i] = wt + ((size_t)(co0 + i * 64 + trow) << 8) + lcx * 8;
        int r  = i * 64 + trow;
        int br = r / 56, bc = r - br * 56;
        pB[i] = xT + (((size_t)nimg * HP + R0 + br + 1) * HP + (bc + 1)) * C_IN + lcx * 8;
    }

    auto stageA2 = [&](int slot, int tk, int part) {   // part0: rows 0-127, part1: 128-255
        const size_t off = ((size_t)(tk >> 2) << 17) + ((tk & 3) << 6);
        bf16_t* dst = &As[slot][0][0] + wid * 512;
        if (part == 0) { gl16(pA[0] + off, dst);        gl16(pA[1] + off, dst + 4096); }
        else           { gl16(pA[2] + off, dst + 8192); gl16(pA[3] + off, dst + 12288); }
    };
    auto stageB2 = [&](int buf, int tk, int part) {    // part0: rows 0-127, part1: 128-223
        const int p  = tk >> 2;
        const int q3 = p / 3;
        const int off = ((q3 - 1) * HP + (p - q3 * 3) - 1) * C_IN + ((tk & 3) << 6);
        bf16_t* dst = &Bs[buf][0][0] + wid * 512;
        if (part == 0) { gl16(pB[0] + off, dst);        gl16(pB[1] + off, dst + 4096); }
        else           { gl16(pB[2] + off, dst + 8192);
                         if (tid < 256) gl16(pB[3] + off, dst + 12288); }
    };

    // ---- LDS byte addresses for asm ds_read (swizzle key = rl&7, invariant over j,m) ----
    const int rl = lane & 15;
    const int kg = lane >> 4;
    const unsigned asBase = (unsigned)(uintptr_t)&As[0][0][0];
    const unsigned bsBase = (unsigned)(uintptr_t)&Bs[0][0][0];
    const unsigned aAddr0 = asBase + (unsigned)((wr * 64 + rl) * 128 + ((kg       ^ (rl & 7)) * 16));
    const unsigned aAddr1 = asBase + (unsigned)((wr * 64 + rl) * 128 + (((4 + kg) ^ (rl & 7)) * 16));
    const unsigned bAddr0 = bsBase + (unsigned)((wc * 112 + rl) * 128 + ((kg       ^ (rl & 7)) * 16));
    const unsigned bAddr1 = bsBase + (unsigned)((wc * 112 + rl) * 128 + (((4 + kg) ^ (rl & 7)) * 16));

    f32x4 acc[4][7];
    #pragma unroll
    for (int m = 0; m < 4; m++)
        #pragma unroll
        for (int j = 0; j < 7; j++)
            acc[m][j] = f32x4{0.f, 0.f, 0.f, 0.f};

    // ---- prologue: B(0) 4 issues, A(0) 4, A(1) 4; vmcnt(4) keeps A(1); barrier ----
    stageB2(0, 0, 0); stageB2(0, 0, 1);
    stageA2(0, 0, 0); stageA2(0, 0, 1);
    stageA2(1, 1, 0); stageA2(1, 1, 1);
    asm volatile("s_waitcnt vmcnt(4)" ::: "memory");
    BAR();
    SCHED0();

    i32x4 A00, A01, A10, A11, A20, A21, A30, A31;
    i32x4 S00, S01, S10, S11, S20, S21;
    int sr = 0;

#define ISSUE_B(D0, D1, OFFS) \
    asm volatile("ds_read_b128 %0, %2 offset:" OFFS "\n\t" \
                 "ds_read_b128 %1, %3 offset:" OFFS \
                 : "=v"(D0), "=v"(D1) : "v"(bT0), "v"(bT1));
#define LGKM(N) asm volatile("s_waitcnt lgkmcnt(" N ")" ::: "memory"); SCHED0();
#define MFMA8(J, X0, X1) \
    PRIO(1); \
    acc[0][J] = MF(A00, X0, acc[0][J]); acc[0][J] = MF(A01, X1, acc[0][J]); \
    acc[1][J] = MF(A10, X0, acc[1][J]); acc[1][J] = MF(A11, X1, acc[1][J]); \
    acc[2][J] = MF(A20, X0, acc[2][J]); acc[2][J] = MF(A21, X1, acc[2][J]); \
    acc[3][J] = MF(A30, X0, acc[3][J]); acc[3][J] = MF(A31, X1, acc[3][J]); \
    PRIO(0);

    #pragma unroll 1
    for (int t = 0; t < NT; ++t) {
        const unsigned aT0 = aAddr0 + (unsigned)sr * 32768u;
        const unsigned aT1 = aAddr1 + (unsigned)sr * 32768u;
        const unsigned bT0 = bAddr0 + (unsigned)(t & 1) * 28672u;
        const unsigned bT1 = bAddr1 + (unsigned)(t & 1) * 28672u;
        const int bnext = (t + 1) & 1;
        const int snext = sr + 2 >= 3 ? sr - 1 : sr + 2;   // (t+2)%3

        // tile-start reads: A (8), bF[0], bF[1]  -> 12 outstanding
        asm volatile(
            "ds_read_b128 %0, %8 offset:0\n\t"
            "ds_read_b128 %1, %9 offset:0\n\t"
            "ds_read_b128 %2, %8 offset:2048\n\t"
            "ds_read_b128 %3, %9 offset:2048\n\t"
            "ds_read_b128 %4, %8 offset:4096\n\t"
            "ds_read_b128 %5, %9 offset:4096\n\t"
            "ds_read_b128 %6, %8 offset:6144\n\t"
            "ds_read_b128 %7, %9 offset:6144"
            : "=v"(A00), "=v"(A01), "=v"(A10), "=v"(A11),
              "=v"(A20), "=v"(A21), "=v"(A30), "=v"(A31)
            : "v"(aT0), "v"(aT1));
        ISSUE_B(S00, S01, "0");
        ISSUE_B(S10, S11, "2048");

        // j=0: +bF[2]; stage B(t+1) lo; drain A+b0 (keep 4)
        ISSUE_B(S20, S21, "4096");
        if (t + 1 < NT) stageB2(bnext, t + 1, 0);
        LGKM("4");
        MFMA8(0, S00, S01);

        // j=1: +bF[3]->slot0; stage B(t+1) hi
        ISSUE_B(S00, S01, "6144");
        if (t + 1 < NT) stageB2(bnext, t + 1, 1);
        LGKM("4");
        MFMA8(1, S10, S11);

        // j=2: +bF[4]->slot1
        ISSUE_B(S10, S11, "8192");
        LGKM("4");
        MFMA8(2, S20, S21);

        // j=3: +bF[5]->slot2; stage A(t+2) lo
        ISSUE_B(S20, S21, "10240");
        if (t + 2 < NT) stageA2(snext, t + 2, 0);
        LGKM("4");
        MFMA8(3, S00, S01);

        // j=4: +bF[6]->slot0
        ISSUE_B(S00, S01, "12288");
        LGKM("4");
        MFMA8(4, S10, S11);

        // j=5: stage A(t+2) hi; drain bF[5]
        if (t + 2 < NT) stageA2(snext, t + 2, 1);
        LGKM("2");
        MFMA8(5, S20, S21);

        // j=6: drain bF[6]
        LGKM("0");
        MFMA8(6, S00, S01);

        // end of tile: counted vmem drain (keep A(t+2) in flight), single barrier
        if (t + 2 < NT)
            asm volatile("s_waitcnt vmcnt(4)" ::: "memory");
        else
            asm volatile("s_waitcnt vmcnt(0)" ::: "memory");
        BAR();
        SCHED0();
        sr = (sr + 1 >= 3) ? 0 : sr + 1;
    }
#undef ISSUE_B
#undef LGKM
#undef MFMA8

    // ---- epilogue: D row(co) = m*16 + 4*(lane>>4)+i, col(px) = wc*112 + j*16 + rl ----
    int hw_off[7];
    #pragma unroll
    for (int j = 0; j < 7; j++) {
        int nn = wc * 112 + j * 16 + rl;
        int br = nn / 56, bc = nn - br * 56;
        hw_off[j] = (R0 + br) * 56 + bc;
    }
    const size_t obase = (size_t)nimg * C_OUT * HW;
    #pragma unroll
    for (int m = 0; m < 4; m++) {
        int cob = co0 + wr * 64 + m * 16 + ((lane >> 4) << 2);
        #pragma unroll
        for (int i = 0; i < 4; i++) {
            int co = cob + i;
            float bv = bias[co];
            float* orow = out + obase + (size_t)co * HW;
            #pragma unroll
            for (int j = 0; j < 7; j++)
                orow[hw_off[j]] = acc[m][j][i] + bv;
        }
    }
}

extern "C" void kernel_launch(void* const* d_in, const int* in_sizes, int n_in,
                              void* d_out, int out_size, void* d_ws, size_t ws_size,
                              hipStream_t stream) {
    const float* x    = (const float*)d_in[0];
    const float* w    = (const float*)d_in[1];
    const float* bias = (const float*)d_in[2];
    float* out = (float*)d_out;

    // workspace: xT halo-padded NHWC bf16 (32*58*58*256*2 = 55.1 MB) then Wt (2.4 MB)
    bf16_t* xT = (bf16_t*)d_ws;
    bf16_t* wt = (bf16_t*)((char*)d_ws + (size_t)NB * HP * HP * C_IN * 2);

    k_halo_zero<<<dim3((NB * 228 * 32 + 255) / 256), dim3(256), 0, stream>>>(xT);
    k_x_nhwc<<<dim3(49, 4, NB), dim3(256), 0, stream>>>(x, xT);
    k_dequant<<<dim3((NQBLK + 255) / 256), dim3(256), 0, stream>>>(w, wt);
    k_conv_gemm<<<dim3(NWG), dim3(512), 0, stream>>>(xT, wt, bias, out);
}

// Round 9
// 260.679 us; speedup vs baseline: 1.3858x; 1.0591x over previous
//
#include <hip/hip_runtime.h>
#include <hip/hip_bf16.h>

typedef __bf16 bf16_t;
typedef __attribute__((ext_vector_type(8))) __bf16 bf16x8;
typedef __attribute__((ext_vector_type(4))) float f32x4;
typedef __attribute__((ext_vector_type(4))) int   i32x4;

#define C_IN   256
#define C_OUT  512
#define HW     3136      // 56*56
#define NB     32        // batch
#define HP     58        // 56 + 2 halo
#define NQBLK  36864     // (512*256*9)/32 quant blocks

// conv-GEMM: BM=256(co) x BN=224(4 img rows) x BK=64; NT=36 tiles (9 pos x 4 ci-chunks)
#define NT   36
#define NWG  896         // 448 px-bands (32 img x 14) x 2 co-blocks

typedef const __attribute__((address_space(1))) unsigned int gu32;
typedef __attribute__((address_space(3))) unsigned int lu32;
__device__ __forceinline__ void gl16(const void* g, void* l) {
    __builtin_amdgcn_global_load_lds((gu32*)g, (lu32*)l, 16, 0, 0);
}
#define BAR()    __builtin_amdgcn_s_barrier()
#define PRIO(x)  __builtin_amdgcn_s_setprio(x)
#define SCHED0() __builtin_amdgcn_sched_barrier(0)

__device__ __forceinline__ bf16x8 asbf(i32x4 v) {
    union { i32x4 a; bf16x8 b; } u; u.a = v; return u.b;
}
__device__ __forceinline__ f32x4 MF(i32x4 a, i32x4 b, f32x4 c) {
    return __builtin_amdgcn_mfma_f32_16x16x32_bf16(asbf(a), asbf(b), c, 0, 0, 0);
}

// ---------------- kernel 1: 6-bit fake-quant + repack to Wt[p][co][ci] (bf16) ----------------
__global__ void k_dequant(const float* __restrict__ w, bf16_t* __restrict__ wt) {
    int b = blockIdx.x * blockDim.x + threadIdx.x;
    if (b >= NQBLK) return;
    const float* src = w + (size_t)b * 32;
    float v[32];
    float amax = 0.f;
    #pragma unroll
    for (int i = 0; i < 32; i += 4) {
        float4 t = *reinterpret_cast<const float4*>(src + i);
        v[i] = t.x; v[i+1] = t.y; v[i+2] = t.z; v[i+3] = t.w;
        amax = fmaxf(amax, fmaxf(fmaxf(fabsf(t.x), fabsf(t.y)),
                                 fmaxf(fabsf(t.z), fabsf(t.w))));
    }
    float scale = amax / 31.0f;
    if (scale == 0.f) scale = 1.f;
    #pragma unroll
    for (int i = 0; i < 32; i++) {
        float q = rintf(v[i] / scale);            // jnp.round = RNE = rintf
        q = fminf(31.f, fmaxf(-32.f, q));
        float dq = q * scale;
        int flat = b * 32 + i;                    // flat over OIHW
        int p    = flat % 9;
        int rest = flat / 9;
        int ci   = rest & 255;
        int co   = rest >> 8;
        wt[((size_t)(p * C_OUT + co) << 8) + ci] = (bf16_t)dq;
    }
}

// ---------------- kernel 1b: zero the 1-pixel halo ring of xT ----------------
__global__ void k_halo_zero(bf16_t* __restrict__ xT) {
    int idx = blockIdx.x * 256 + threadIdx.x;
    if (idx >= NB * 228 * 32) return;
    int c8 = idx & 31;
    int t  = idx >> 5;
    int p  = t % 228;
    int n  = t / 228;
    int hh, ww;
    if      (p < 58)  { hh = 0;           ww = p; }
    else if (p < 116) { hh = 57;          ww = p - 58; }
    else if (p < 172) { hh = p - 116 + 1; ww = 0; }
    else              { hh = p - 172 + 1; ww = 57; }
    size_t e = (((size_t)n * HP + hh) * HP + ww) * C_IN + c8 * 8;
    *reinterpret_cast<uint4*>(xT + e) = make_uint4(0, 0, 0, 0);
}

// ------- kernel 2: x NCHW fp32 -> halo-padded NHWC bf16 (xT[n][58][58][ci]) -------
__global__ void k_x_nhwc(const float* __restrict__ x, bf16_t* __restrict__ xT) {
    __shared__ float tile[64][65];
    const int n   = blockIdx.z;
    const int cb  = blockIdx.y * 64;
    const int hwb = blockIdx.x * 64;
    const int t   = threadIdx.x;

    const int col = t & 63;
    const int r0  = t >> 6;
    #pragma unroll
    for (int k = 0; k < 16; k++) {
        int r = r0 * 16 + k;
        tile[r][col] = x[((size_t)(n * C_IN + cb + r)) * HW + hwb + col];
    }
    __syncthreads();

    const int j  = t >> 2;
    const int co = (t & 3) * 16;
    const int hw = hwb + j;
    const int hh = hw / 56, ww = hw - hh * 56;
    __align__(16) bf16_t vals[16];
    #pragma unroll
    for (int k = 0; k < 16; k++)
        vals[k] = (bf16_t)tile[co + k][j];
    bf16_t* dst = xT + (((size_t)n * HP + hh + 1) * HP + (ww + 1)) * C_IN + cb + co;
    *reinterpret_cast<uint4*>(dst)     = *reinterpret_cast<uint4*>(&vals[0]);
    *reinterpret_cast<uint4*>(dst + 8) = *reinterpret_cast<uint4*>(&vals[8]);
}

// ------------- kernel 3: implicit-GEMM conv, A-reg double-buffered + counted-lgkm pipeline -------------
// Geometry = R8: 8 waves 4(M)x2(N), wave 64(co)x112(px), acc[4][7]; K-tile = 64 ci of one position.
// LDS: As[3][256][64] (96KB triple) + Bs[2][224][64] (56KB double) = 152 KB.
// NEW vs R8: A-fragments for tile t+1 are ds_read DURING tile t (2 per j-group, j1..j4) into the
// ping-pong reg set; tile t's MFMAs use regs loaded last tile. Tile-start burst 12->6 reads.
//
// lgkm FIFO ledger (per wave; X1,X2 = prev tile's last 2 A'-reads, still in flight):
//  start: issue b0 pair, b1 pair                        out=[X1,X2,b0,b0,b1,b1]
//  j0: +b2 pair; stage A(t+2)lo;  LGKM(4)  drains X,b0  -> MFMA8(0,b0regs)
//  j1: +b3 pair, +A'0,A'1; stage A(t+2)hi; LGKM(6)  drains b1 -> MFMA8(1)
//  j2: +b4 pair, +A'2,A'3; stage B(t+1)lo; LGKM(8)  drains b2 -> MFMA8(2)
//  j3: +b5 pair, +A'4,A'5; stage B(t+1)hi; LGKM(10) drains b3 -> MFMA8(3)
//  j4: +b6 pair, +A'6,A'7;                 LGKM(10) drains A'0,A'1,b4 -> MFMA8(4)
//  j5:                                     LGKM(6)  drains A'2,A'3,b5 -> MFMA8(5)
//  j6:                                     LGKM(2)  drains A'4,A'5,b6 -> MFMA8(6)
//  end: vmcnt(0) (stages >=3 groups old: free) ; BAR. Leftover [A'6,A'7] -> next tile's X.
// A' reads target As[(t+1)%3]: staged during t-1, drained by t-1's end vmcnt(0)+BAR. Writes
// during t go to As[(t+2)%3] / Bs[(t+1)&1]: disjoint from all reads during t. Race-free.
// XOR swizzle chunk^=row&7 on 128B rows (0 conflicts, R3/R6/R8); pre-swizzled global source.
__global__ __launch_bounds__(512, 2) void k_conv_gemm(
    const bf16_t* __restrict__ xT, const bf16_t* __restrict__ wt,
    const float* __restrict__ bias, float* __restrict__ out)
{
    __shared__ __align__(16) bf16_t As[3][256][64];   // 96 KB
    __shared__ __align__(16) bf16_t Bs[2][224][64];   // 56 KB

    const int tid  = threadIdx.x;
    const int lane = tid & 63;
    const int wid  = tid >> 6;
    const int wr   = wid >> 1;      // 0..3 -> co slice of 64
    const int wc   = wid & 1;       // 0..1 -> px slice of 112

    // bijective XCD swizzle: 896 = 8 x 112; co-fastest within chunk
    const int orig  = blockIdx.x;
    const int wgid  = (orig & 7) * 112 + (orig >> 3);
    const int co0   = (wgid & 1) * 256;
    const int sband = wgid >> 1;                 // 0..447
    const int nimg  = sband / 14;
    const int R0    = (sband - nimg * 14) * 4;   // first output row of band

    // ---- staging geometry: per 64-row issue, thread covers row tid>>3, 16B chunk tid&7
    const int trow = tid >> 3;                   // 0..63
    const int lcx  = (tid & 7) ^ (trow & 7);     // pre-swizzled source chunk (key = row&7)

    const bf16_t* pA[4];
    const bf16_t* pB[4];
    #pragma unroll
    for (int i = 0; i < 4; i++) {
        pA[i] = wt + ((size_t)(co0 + i * 64 + trow) << 8) + lcx * 8;
        int r  = i * 64 + trow;
        int br = r / 56, bc = r - br * 56;
        pB[i] = xT + (((size_t)nimg * HP + R0 + br + 1) * HP + (bc + 1)) * C_IN + lcx * 8;
    }

    auto stageA2 = [&](int slot, int tk, int part) {   // part0: rows 0-127, part1: 128-255
        const size_t off = ((size_t)(tk >> 2) << 17) + ((tk & 3) << 6);
        bf16_t* dst = &As[slot][0][0] + wid * 512;
        if (part == 0) { gl16(pA[0] + off, dst);        gl16(pA[1] + off, dst + 4096); }
        else           { gl16(pA[2] + off, dst + 8192); gl16(pA[3] + off, dst + 12288); }
    };
    auto stageB2 = [&](int buf, int tk, int part) {    // part0: rows 0-127, part1: 128-223
        const int p  = tk >> 2;
        const int q3 = p / 3;
        const int off = ((q3 - 1) * HP + (p - q3 * 3) - 1) * C_IN + ((tk & 3) << 6);
        bf16_t* dst = &Bs[buf][0][0] + wid * 512;
        if (part == 0) { gl16(pB[0] + off, dst);        gl16(pB[1] + off, dst + 4096); }
        else           { gl16(pB[2] + off, dst + 8192);
                         if (tid < 256) gl16(pB[3] + off, dst + 12288); }
    };

    // ---- LDS byte addresses for asm ds_read (swizzle key = rl&7, invariant over j,m) ----
    const int rl = lane & 15;
    const int kg = lane >> 4;
    const unsigned asBase = (unsigned)(uintptr_t)&As[0][0][0];
    const unsigned bsBase = (unsigned)(uintptr_t)&Bs[0][0][0];
    const unsigned aAddr0 = asBase + (unsigned)((wr * 64 + rl) * 128 + ((kg       ^ (rl & 7)) * 16));
    const unsigned aAddr1 = asBase + (unsigned)((wr * 64 + rl) * 128 + (((4 + kg) ^ (rl & 7)) * 16));
    const unsigned bAddr0 = bsBase + (unsigned)((wc * 112 + rl) * 128 + ((kg       ^ (rl & 7)) * 16));
    const unsigned bAddr1 = bsBase + (unsigned)((wc * 112 + rl) * 128 + (((4 + kg) ^ (rl & 7)) * 16));

    f32x4 acc[4][7];
    #pragma unroll
    for (int m = 0; m < 4; m++)
        #pragma unroll
        for (int j = 0; j < 7; j++)
            acc[m][j] = f32x4{0.f, 0.f, 0.f, 0.f};

#define RD2(D0, D1, A0, A1, OFFS) \
    asm volatile("ds_read_b128 %0, %2 offset:" OFFS "\n\t" \
                 "ds_read_b128 %1, %3 offset:" OFFS \
                 : "=v"(D0), "=v"(D1) : "v"(A0), "v"(A1));
#define LGKM(N) asm volatile("s_waitcnt lgkmcnt(" N ")" ::: "memory"); SCHED0();
#define MFMA8(AA, J, X0, X1) \
    PRIO(1); \
    acc[0][J] = MF(AA##00, X0, acc[0][J]); acc[0][J] = MF(AA##01, X1, acc[0][J]); \
    acc[1][J] = MF(AA##10, X0, acc[1][J]); acc[1][J] = MF(AA##11, X1, acc[1][J]); \
    acc[2][J] = MF(AA##20, X0, acc[2][J]); acc[2][J] = MF(AA##21, X1, acc[2][J]); \
    acc[3][J] = MF(AA##30, X0, acc[3][J]); acc[3][J] = MF(AA##31, X1, acc[3][J]); \
    PRIO(0);

#define TILE(AC, AN, T, SR1, SR2, BCUR) do {                                  \
    const unsigned bT0 = bAddr0 + (unsigned)(BCUR) * 28672u;                  \
    const unsigned bT1 = bAddr1 + (unsigned)(BCUR) * 28672u;                  \
    const unsigned nT0 = aAddr0 + (unsigned)(SR1) * 32768u;                   \
    const unsigned nT1 = aAddr1 + (unsigned)(SR1) * 32768u;                   \
    RD2(S00, S01, bT0, bT1, "0");                                             \
    RD2(S10, S11, bT0, bT1, "2048");                                          \
    /* j0 */                                                                  \
    RD2(S20, S21, bT0, bT1, "4096");                                          \
    if ((T) + 2 < NT) stageA2((SR2), (T) + 2, 0);                             \
    LGKM("4");  MFMA8(AC, 0, S00, S01);                                       \
    /* j1 */                                                                  \
    RD2(S00, S01, bT0, bT1, "6144");                                          \
    RD2(AN##00, AN##01, nT0, nT1, "0");                                       \
    if ((T) + 2 < NT) stageA2((SR2), (T) + 2, 1);                             \
    LGKM("6");  MFMA8(AC, 1, S10, S11);                                       \
    /* j2 */                                                                  \
    RD2(S10, S11, bT0, bT1, "8192");                                          \
    RD2(AN##10, AN##11, nT0, nT1, "2048");                                    \
    if ((T) + 1 < NT) stageB2(((T) + 1) & 1, (T) + 1, 0);                     \
    LGKM("8");  MFMA8(AC, 2, S20, S21);                                       \
    /* j3 */                                                                  \
    RD2(S20, S21, bT0, bT1, "10240");                                         \
    RD2(AN##20, AN##21, nT0, nT1, "4096");                                    \
    if ((T) + 1 < NT) stageB2(((T) + 1) & 1, (T) + 1, 1);                     \
    LGKM("10"); MFMA8(AC, 3, S00, S01);                                       \
    /* j4 */                                                                  \
    RD2(S00, S01, bT0, bT1, "12288");                                         \
    RD2(AN##30, AN##31, nT0, nT1, "6144");                                    \
    LGKM("10"); MFMA8(AC, 4, S10, S11);                                       \
    /* j5 */                                                                  \
    LGKM("6");  MFMA8(AC, 5, S20, S21);                                       \
    /* j6 */                                                                  \
    LGKM("2");  MFMA8(AC, 6, S00, S01);                                       \
    asm volatile("s_waitcnt vmcnt(0)" ::: "memory");                          \
    BAR();                                                                    \
    SCHED0();                                                                 \
} while (0)

    i32x4 Ea00, Ea01, Ea10, Ea11, Ea20, Ea21, Ea30, Ea31;
    i32x4 Eb00, Eb01, Eb10, Eb11, Eb20, Eb21, Eb30, Eb31;
    i32x4 S00, S01, S10, S11, S20, S21;

    // ---- prologue: stage A(0),A(1),B(0); drain; barrier; preload A(0) frags ----
    stageA2(0, 0, 0); stageA2(0, 0, 1);
    stageA2(1, 1, 0); stageA2(1, 1, 1);
    stageB2(0, 0, 0); stageB2(0, 0, 1);
    asm volatile("s_waitcnt vmcnt(0)" ::: "memory");
    BAR();
    SCHED0();
    RD2(Ea00, Ea01, aAddr0, aAddr1, "0");
    RD2(Ea10, Ea11, aAddr0, aAddr1, "2048");
    RD2(Ea20, Ea21, aAddr0, aAddr1, "4096");
    RD2(Ea30, Ea31, aAddr0, aAddr1, "6144");

    int sr = 0;
    #pragma unroll 1
    for (int t = 0; t < NT; t += 2) {
        const int sr1 = (sr + 1 >= 3) ? sr - 2 : sr + 1;
        const int sr2 = (sr + 2 >= 3) ? sr - 1 : sr + 2;
        TILE(Ea, Eb, t,     sr1, sr2, 0);
        TILE(Eb, Ea, t + 1, sr2, sr,  1);
        sr = sr2;
    }
    // protect epilogue register reuse from the 2 still-in-flight A' reads
    asm volatile("s_waitcnt lgkmcnt(0)" ::: "memory");
    SCHED0();

#undef RD2
#undef LGKM
#undef MFMA8
#undef TILE

    // ---- epilogue: D row(co) = m*16 + 4*(lane>>4)+i, col(px) = wc*112 + j*16 + rl ----
    int hw_off[7];
    #pragma unroll
    for (int j = 0; j < 7; j++) {
        int nn = wc * 112 + j * 16 + rl;
        int br = nn / 56, bc = nn - br * 56;
        hw_off[j] = (R0 + br) * 56 + bc;
    }
    const size_t obase = (size_t)nimg * C_OUT * HW;
    #pragma unroll
    for (int m = 0; m < 4; m++) {
        int cob = co0 + wr * 64 + m * 16 + ((lane >> 4) << 2);
        #pragma unroll
        for (int i = 0; i < 4; i++) {
            int co = cob + i;
            float bv = bias[co];
            float* orow = out + obase + (size_t)co * HW;
            #pragma unroll
            for (int j = 0; j < 7; j++)
                orow[hw_off[j]] = acc[m][j][i] + bv;
        }
    }
}

extern "C" void kernel_launch(void* const* d_in, const int* in_sizes, int n_in,
                              void* d_out, int out_size, void* d_ws, size_t ws_size,
                              hipStream_t stream) {
    const float* x    = (const float*)d_in[0];
    const float* w    = (const float*)d_in[1];
    const float* bias = (const float*)d_in[2];
    float* out = (float*)d_out;

    // workspace: xT halo-padded NHWC bf16 (32*58*58*256*2 = 55.1 MB) then Wt (2.4 MB)
    bf16_t* xT = (bf16_t*)d_ws;
    bf16_t* wt = (bf16_t*)((char*)d_ws + (size_t)NB * HP * HP * C_IN * 2);

    k_halo_zero<<<dim3((NB * 228 * 32 + 255) / 256), dim3(256), 0, stream>>>(xT);
    k_x_nhwc<<<dim3(49, 4, NB), dim3(256), 0, stream>>>(x, xT);
    k_dequant<<<dim3((NQBLK + 255) / 256), dim3(256), 0, stream>>>(w, wt);
    k_conv_gemm<<<dim3(NWG), dim3(512), 0, stream>>>(xT, wt, bias, out);
}